// Round 6
// baseline (536.519 us; speedup 1.0000x reference)
//
#include <hip/hip_runtime.h>
#include <cstdint>
#include <cstddef>

#define M_TOT 8192
#define N_TOT 4096
#define K_TOT 4096
#define RANK  16

// ---- 256x256 GEMM geometry, 1-barrier-per-tile counted-lgkm schedule, 32x32x16 MFMA ----
#define BM 256
#define BN 256
#define BK 64
#define NT (K_TOT / BK)   // 64 K-tiles

typedef float f32x4 __attribute__((ext_vector_type(4)));
typedef float f32x16 __attribute__((ext_vector_type(16)));
typedef __bf16 bf16x8 __attribute__((ext_vector_type(8)));
typedef unsigned short u16x8 __attribute__((ext_vector_type(8)));

__device__ __forceinline__ unsigned short f32_to_bf16(float f) {
    union { float f; uint32_t u; } v; v.f = f;
    uint32_t r = v.u + (0x7fffu + ((v.u >> 16) & 1u));
    return (unsigned short)(r >> 16);
}

// width-16 async global->LDS. dst is wave-uniform base; HW writes lane i at base + i*16B.
__device__ __forceinline__ void gload_lds16(const void* g, void* l) {
    __builtin_amdgcn_global_load_lds(
        (const __attribute__((address_space(1))) void*)g,
        (__attribute__((address_space(3))) void*)l,
        16, 0, 0);
}

// LDS byte address (as(3) pointers are the raw LDS byte offset)
__device__ __forceinline__ unsigned lds_addr(const void* p) {
    return (unsigned)(uintptr_t)(const __attribute__((address_space(3))) void*)p;
}

// Inline-asm ds_read_b128: opaque to alias analysis -> no implicit vmcnt drains.
// Volatile asm preserves mutual order, so issue order == lgkmcnt retire order.
// Consumers fenced by counted lgkmcnt + sched_barrier(0) (rule #18).
__device__ __forceinline__ bf16x8 dsr(unsigned addr) {
    bf16x8 r;
    asm volatile("ds_read_b128 %0, %1" : "=v"(r) : "v"(addr));
    return r;
}

// ---------------- x fp32 -> bf16, 8 elems/thread, 16B stores ----------------
__global__ __launch_bounds__(256) void convert_x_kernel(const float* __restrict__ x,
                                                        unsigned short* __restrict__ xb,
                                                        int n8) {
    int i = blockIdx.x * 256 + threadIdx.x;
    if (i >= n8) return;
    float4 a = ((const float4*)x)[2 * (size_t)i];
    float4 b = ((const float4*)x)[2 * (size_t)i + 1];
    u16x8 o;
    o[0] = f32_to_bf16(a.x); o[1] = f32_to_bf16(a.y);
    o[2] = f32_to_bf16(a.z); o[3] = f32_to_bf16(a.w);
    o[4] = f32_to_bf16(b.x); o[5] = f32_to_bf16(b.y);
    o[6] = f32_to_bf16(b.z); o[7] = f32_to_bf16(b.w);
    *(u16x8*)&xb[(size_t)i * 8] = o;
}

// ---- W = dequant(q,scales) + up@down, bf16 [OUT][IN]. 4 rows/block. ----
__global__ __launch_bounds__(256) void build_w_kernel(const int* __restrict__ q,
                                                      const float* __restrict__ scales,
                                                      const float* __restrict__ up,
                                                      const float* __restrict__ down,
                                                      unsigned short* __restrict__ W) {
    const int o0 = blockIdx.x * 4;
    const int t = threadIdx.x;
    __shared__ float u[4][RANK];
    if (t < 64) u[t >> 4][t & 15] = up[(o0 + (t >> 4)) * RANK + (t & 15)];
    __syncthreads();

#pragma unroll
    for (int cc = 0; cc < 2; cc++) {
        const int c = t + 256 * cc;        // 8-elem chunk index, 0..511
        const int k0 = c * 8;
        float acc[4][8];
#pragma unroll
        for (int row = 0; row < 4; row++) {
            const int o = o0 + row;
            int4 qa = *(const int4*)&q[(size_t)o * K_TOT + k0];
            int4 qb = *(const int4*)&q[(size_t)o * K_TOT + k0 + 4];
            const float s = scales[o * (K_TOT / 32) + (k0 >> 5)];
            acc[row][0] = (float)(qa.x - 128) * s;
            acc[row][1] = (float)(qa.y - 128) * s;
            acc[row][2] = (float)(qa.z - 128) * s;
            acc[row][3] = (float)(qa.w - 128) * s;
            acc[row][4] = (float)(qb.x - 128) * s;
            acc[row][5] = (float)(qb.y - 128) * s;
            acc[row][6] = (float)(qb.z - 128) * s;
            acc[row][7] = (float)(qb.w - 128) * s;
        }
#pragma unroll
        for (int r = 0; r < RANK; r++) {
            float4 da = *(const float4*)&down[r * K_TOT + k0];
            float4 db = *(const float4*)&down[r * K_TOT + k0 + 4];
#pragma unroll
            for (int row = 0; row < 4; row++) {
                const float ur = u[row][r];
                acc[row][0] += ur * da.x; acc[row][1] += ur * da.y;
                acc[row][2] += ur * da.z; acc[row][3] += ur * da.w;
                acc[row][4] += ur * db.x; acc[row][5] += ur * db.y;
                acc[row][6] += ur * db.z; acc[row][7] += ur * db.w;
            }
        }
#pragma unroll
        for (int row = 0; row < 4; row++) {
            u16x8 o8;
#pragma unroll
            for (int j = 0; j < 8; j++) o8[j] = f32_to_bf16(acc[row][j]);
            *(u16x8*)&W[(size_t)(o0 + row) * K_TOT + k0] = o8;
        }
    }
}

// raw barrier (no vmcnt drain); memory clobbers pin LDS-DMA/VMEM issue order.
#define BARRIER() do { asm volatile("" ::: "memory"); \
                       __builtin_amdgcn_s_barrier(); \
                       asm volatile("" ::: "memory"); } while (0)
#define WAITLG8() asm volatile("s_waitcnt lgkmcnt(8)" ::: "memory")
#define WAITLG4() asm volatile("s_waitcnt lgkmcnt(4)" ::: "memory")
#define WAITLG0() asm volatile("s_waitcnt lgkmcnt(0)" ::: "memory")
#define VMCNT0()  asm volatile("s_waitcnt vmcnt(0)" ::: "memory")
#define SCHED0()  __builtin_amdgcn_sched_barrier(0)

// ---------------- C[m][n] = sum_k A[m][k]*B[n][k] + bias[n]  (bf16 K-major) ----------------
// 256x256 tile, BK=64, 8 waves (2Mx4N), mfma_f32_32x32x16_bf16 (measured 2495 TF pipe vs
// 2075-2176 for 16x16x32: -17% MFMA floor, half the instructions -> half the issue cycles).
// Per wave-tile (128x64): 4 m-tiles x 2 n-tiles x 4 k-steps = 32 MFMA, 24 ds_read_b128
// (A 16 + B 8 -- same LDS bytes as the 16x16 version).
// Schedule per K-tile (ONE barrier): stage all 8 gloads of t+1 -> R1(8)+R2(8) ->
// lgkm(8) Q1(8 MFMA) -> R3(8) -> lgkm(8) Q2 -> lgkm(4) Q3 -> lgkm(0) Q4 -> vmcnt(0) barrier.
// Frag mapping (32x32x16): A row=lane&31, k=(lane>>5)*8+j; B col=lane&31 same k;
// D col=lane&31, row=(reg&3)+8*(reg>>2)+4*(lane>>5)  [m74/m101].
// LDS: 2 buf x {A,B} x 2 halves x [128 rows][64 cols] bf16 = 128 KB.
// Swizzle: 16B k-slot s of row r stored at slot s^(r&7); staging pre-swizzles the GLOBAL
// source (global_load_lds dst stays linear); reads apply the same XOR (s = ks*2 + kh).
__global__ __launch_bounds__(512, 2) void gemm_bt_kernel(const unsigned short* __restrict__ A,
                                                         const unsigned short* __restrict__ B,
                                                         const float* __restrict__ bias,
                                                         float* __restrict__ C) {
    __shared__ unsigned short As[2][2][128 * BK];   // [buf][half][row*64+col] 64 KB
    __shared__ unsigned short Bs[2][2][128 * BK];   // 64 KB

    const int tid  = (int)threadIdx.x;
    const int wave = tid >> 6;        // 0..7
    const int lane = tid & 63;
    const int wm   = wave >> 2;       // 0..1 : A half / 128-row strip
    const int wn   = wave & 3;        // 0..3 : 64-col strip
    const int wbh  = wn >> 1;         // B half
    const int wbr  = (wn & 1) * 64;   // row base within B half

    // XCD-bijective swizzle: nwg=512, 8 XCDs, 64 contiguous tiles per XCD
    int lin = (int)(blockIdx.y * gridDim.x + blockIdx.x);
    lin = (lin & 7) * 64 + (lin >> 3);
    const int tile_n = (lin & 15) * BN;   // 16 N-tiles
    const int tile_m = (lin >> 4) * BM;   // 32 M-tiles

    // staging: instr covers rows i*64 + tid/8 of a half; lane's 16B chunk fetches
    // global k-group (tid&7) ^ (row&7)  (inverse swizzle applied at the source)
    const int srow  = tid >> 3;                         // 0..63
    const int sk    = ((tid & 7) ^ (srow & 7)) * 8;     // elem offset in 64-col group
    const int wbase = wave * 512;                       // wave-uniform LDS elem base

    // fragment-read constants (mfma_32x32x16: row/col = lane&31, k-half = lane>>5)
    const int l32 = lane & 31;
    const int kh  = lane >> 5;        // 0..1
    const int swz = l32 & 7;
    // byte offset of the 16B slot holding k = ks*16 + kh*8 .. +8 for row l32
    int sl[4];
#pragma unroll
    for (int ks = 0; ks < 4; ks++) sl[ks] = (((ks << 1) | kh) ^ swz) * 16;

    const unsigned short* aBase = A + (size_t)(tile_m + srow) * K_TOT + sk;
    const unsigned short* bBase = B + (size_t)(tile_n + srow) * K_TOT + sk;

#define STAGE_A(d, h, t) do { \
    gload_lds16(aBase + (size_t)((h) * 128) * K_TOT + (size_t)(t) * BK, &As[d][h][wbase]); \
    gload_lds16(aBase + (size_t)((h) * 128 + 64) * K_TOT + (size_t)(t) * BK, &As[d][h][4096 + wbase]); \
  } while (0)
#define STAGE_B(d, h, t) do { \
    gload_lds16(bBase + (size_t)((h) * 128) * K_TOT + (size_t)(t) * BK, &Bs[d][h][wbase]); \
    gload_lds16(bBase + (size_t)((h) * 128 + 64) * K_TOT + (size_t)(t) * BK, &Bs[d][h][4096 + wbase]); \
  } while (0)

    f32x16 acc[4][2];
#pragma unroll
    for (int i = 0; i < 4; i++)
#pragma unroll
        for (int j = 0; j < 2; j++)
#pragma unroll
            for (int e = 0; e < 16; e++) acc[i][j][e] = 0.f;

    // prologue: stage tile 0 fully, drain, barrier
    STAGE_A(0, 0, 0); STAGE_A(0, 1, 0);
    STAGE_B(0, 0, 0); STAGE_B(0, 1, 0);
    VMCNT0();
    BARRIER();

    for (int t = 0; t < NT; ++t) {
        const int cur = t & 1, nxt = cur ^ 1;

        // stage ALL of tile t+1 up front: max vmcnt issue-to-drain distance (~full tile)
        if (t + 1 < NT) {
            STAGE_B(nxt, 0, t + 1); STAGE_B(nxt, 1, t + 1);
            STAGE_A(nxt, 0, t + 1); STAGE_A(nxt, 1, t + 1);
        }

        // per-tile LDS byte bases: row l32 of this wave's A half / B strip
        const unsigned AhB = lds_addr(&As[cur][wm][l32 * BK]);
        const unsigned BhB = lds_addr(&Bs[cur][wbh][(wbr + l32) * BK]);

        bf16x8 aL[2][2], aM[2][2], aN[2][2], aO[2][2];  // [mi][ks-pair]
        bf16x8 bL[2][2], bH[2][2];                       // [ni][ks-pair]

        // R1 (8): B[ni0-1][ks0-1] + A[mi0-1][ks0-1]        -> feeds Q1
#pragma unroll
        for (int ni = 0; ni < 2; ni++) {
            bL[ni][0] = dsr(BhB + ni * 4096 + sl[0]);
            bL[ni][1] = dsr(BhB + ni * 4096 + sl[1]);
        }
#pragma unroll
        for (int mi = 0; mi < 2; mi++) {
            aL[mi][0] = dsr(AhB + mi * 4096 + sl[0]);
            aL[mi][1] = dsr(AhB + mi * 4096 + sl[1]);
        }
        // R2 (8): A[mi2-3][ks0-1] + B[ni0-1][ks2-3]        -> feeds Q2 (and bH for Q3/Q4)
#pragma unroll
        for (int mi = 0; mi < 2; mi++) {
            aM[mi][0] = dsr(AhB + (mi + 2) * 4096 + sl[0]);
            aM[mi][1] = dsr(AhB + (mi + 2) * 4096 + sl[1]);
        }
#pragma unroll
        for (int ni = 0; ni < 2; ni++) {
            bH[ni][0] = dsr(BhB + ni * 4096 + sl[2]);
            bH[ni][1] = dsr(BhB + ni * 4096 + sl[3]);
        }

        // Q1: wait R1 only (R2 drains during MFMAs): acc[0-1][*] ks0-1
        WAITLG8();
        SCHED0();
        __builtin_amdgcn_s_setprio(1);
#pragma unroll
        for (int mi = 0; mi < 2; mi++)
#pragma unroll
            for (int ni = 0; ni < 2; ni++)
#pragma unroll
                for (int ks = 0; ks < 2; ks++)
                    acc[mi][ni] = __builtin_amdgcn_mfma_f32_32x32x16_bf16(aL[mi][ks], bL[ni][ks], acc[mi][ni], 0, 0, 0);
        __builtin_amdgcn_s_setprio(0);
        SCHED0();

        // R3 (8): A[mi0-1][ks2-3] then A[mi2-3][ks2-3]     -> feeds Q3/Q4
#pragma unroll
        for (int mi = 0; mi < 2; mi++) {
            aN[mi][0] = dsr(AhB + mi * 4096 + sl[2]);
            aN[mi][1] = dsr(AhB + mi * 4096 + sl[3]);
        }
#pragma unroll
        for (int mi = 0; mi < 2; mi++) {
            aO[mi][0] = dsr(AhB + (mi + 2) * 4096 + sl[2]);
            aO[mi][1] = dsr(AhB + (mi + 2) * 4096 + sl[3]);
        }

        // Q2: wait R2 (R3's 8 may stay outstanding): acc[2-3][*] ks0-1
        WAITLG8();
        SCHED0();
        __builtin_amdgcn_s_setprio(1);
#pragma unroll
        for (int mi = 0; mi < 2; mi++)
#pragma unroll
            for (int ni = 0; ni < 2; ni++)
#pragma unroll
                for (int ks = 0; ks < 2; ks++)
                    acc[mi + 2][ni] = __builtin_amdgcn_mfma_f32_32x32x16_bf16(aM[mi][ks], bL[ni][ks], acc[mi + 2][ni], 0, 0, 0);
        __builtin_amdgcn_s_setprio(0);
        SCHED0();

        // Q3: wait first half of R3 (aN): acc[0-1][*] ks2-3
        WAITLG4();
        SCHED0();
        __builtin_amdgcn_s_setprio(1);
#pragma unroll
        for (int mi = 0; mi < 2; mi++)
#pragma unroll
            for (int ni = 0; ni < 2; ni++)
#pragma unroll
                for (int ks = 0; ks < 2; ks++)
                    acc[mi][ni] = __builtin_amdgcn_mfma_f32_32x32x16_bf16(aN[mi][ks], bH[ni][ks], acc[mi][ni], 0, 0, 0);
        __builtin_amdgcn_s_setprio(0);
        SCHED0();

        // Q4: all reads done: acc[2-3][*] ks2-3. lgkm(0) also guarantees block-wide
        // read-completion before the boundary barrier (WAR vs next tile's stages).
        WAITLG0();
        SCHED0();
        __builtin_amdgcn_s_setprio(1);
#pragma unroll
        for (int mi = 0; mi < 2; mi++)
#pragma unroll
            for (int ni = 0; ni < 2; ni++)
#pragma unroll
                for (int ks = 0; ks < 2; ks++)
                    acc[mi + 2][ni] = __builtin_amdgcn_mfma_f32_32x32x16_bf16(aO[mi][ks], bH[ni][ks], acc[mi + 2][ni], 0, 0, 0);
        __builtin_amdgcn_s_setprio(0);
        SCHED0();

        VMCNT0();       // t+1's 8 stage loads issued a full tile ago: ~free drain;
        BARRIER();      // boundary makes their LDS writes visible for t+1's reads
    }

    // epilogue (32x32 D layout): col = lane&31, row = (reg&3) + 8*(reg>>2) + 4*kh
#pragma unroll
    for (int ni = 0; ni < 2; ni++) {
        const int col = tile_n + wn * 64 + ni * 32 + l32;
        const float bv = bias[col];
#pragma unroll
        for (int mi = 0; mi < 4; mi++) {
#pragma unroll
            for (int reg = 0; reg < 16; reg++) {
                const int row = tile_m + wm * 128 + mi * 32 + (reg & 3) + 8 * (reg >> 2) + 4 * kh;
                C[(size_t)row * N_TOT + col] = acc[mi][ni][reg] + bv;
            }
        }
    }
#undef STAGE_A
#undef STAGE_B
}

extern "C" void kernel_launch(void* const* d_in, const int* in_sizes, int n_in,
                              void* d_out, int out_size, void* d_ws, size_t ws_size,
                              hipStream_t stream) {
    const float* x      = (const float*)d_in[0];
    const int*   q      = (const int*)d_in[1];
    const float* scales = (const float*)d_in[2];
    const float* up     = (const float*)d_in[3];
    const float* down   = (const float*)d_in[4];
    const float* bias   = (const float*)d_in[5];
    float* out = (float*)d_out;

    unsigned short* xb = (unsigned short*)d_ws;                 // 8192*4096 bf16 = 64 MB
    unsigned short* wb = xb + (size_t)M_TOT * K_TOT;            // 4096*4096 bf16 = 32 MB

    const int n8 = M_TOT * K_TOT / 8;
    convert_x_kernel<<<n8 / 256, 256, 0, stream>>>(x, xb, n8);
    build_w_kernel<<<N_TOT / 4, 256, 0, stream>>>(q, scales, up, down, wb);
    gemm_bt_kernel<<<dim3(N_TOT / BN, M_TOT / BM), 512, 0, stream>>>(xb, wb, bias, out);
}